// Round 4
// baseline (360.440 us; speedup 1.0000x reference)
//
#include <hip/hip_runtime.h>

// B=8, T=8, S=500, F_IN=32, F=F_OUT=64, K=3, L=3
#define BB 8
#define TT 8
#define SS 500
#define FIN 32
#define FF 64
#define KP 512     // padded K (s') for bf16 spatial operands
#define RK 200     // LDS row stride (shorts) for hmix A-tile (192 k + pad)

typedef short bf16x8 __attribute__((ext_vector_type(8)));
typedef float floatx4 __attribute__((ext_vector_type(4)));

__device__ __forceinline__ unsigned f2bf(float x) {
    unsigned u = __builtin_bit_cast(unsigned, x);
    return (u + 0x7FFFu + ((u >> 16) & 1u)) >> 16;   // RNE bf16 in low 16
}

// ---------------------------------------------------------------------------
// prep: Asb[512][512] bf16 (zero-padded) + HcatT[l][f][k=192] bf16
//       HcatT[l][f][m*64+j] = H[l][m][j][f]
// ---------------------------------------------------------------------------
__global__ __launch_bounds__(256) void prep_k(const float* __restrict__ As,
                                              const float* __restrict__ H,
                                              unsigned short* __restrict__ Asb,
                                              unsigned short* __restrict__ Hct) {
    int idx = blockIdx.x * 256 + threadIdx.x;
    if (idx < KP * KP) {
        int s = idx >> 9, k = idx & 511;
        unsigned short v = 0;
        if (s < SS && k < SS) v = (unsigned short)f2bf(As[(size_t)s * SS + k]);
        Asb[idx] = v;
    } else {
        int j = idx - KP * KP;          // [0, 3*64*192)
        if (j < 3 * 64 * 192) {
            int l = j / (64 * 192);
            int rem = j - l * (64 * 192);
            int f = rem / 192;
            int k = rem - f * 192;
            int m = k >> 6, jj = k & 63;
            Hct[j] = (unsigned short)f2bf(H[(((size_t)l * 3 + m) * FF + jj) * FF + f]);
        }
    }
}

// ---------------------------------------------------------------------------
// lin1tmix: xf = x@W1^T + b1 ; p = At.xf ; e1 = s0 xf + s2 p ;
//           rT1 = bf16-T(s1 xf + s3 p)
// grid (32 s-tiles of 16, 8 b), block 256
// ---------------------------------------------------------------------------
__global__ __launch_bounds__(256) void lin1tmix_k(const float* __restrict__ x,
                                                  const float* __restrict__ W1,
                                                  const float* __restrict__ b1,
                                                  const float* __restrict__ At,
                                                  const float* __restrict__ sc,
                                                  float* __restrict__ xf,
                                                  float* __restrict__ e1,
                                                  unsigned short* __restrict__ rT1) {
    __shared__ float Wl[FIN][FF];
    __shared__ float bl[FF];
    __shared__ float Atl[64];
    __shared__ float scl[4];
    __shared__ float Xs[TT][16][FIN + 1];
    __shared__ float Yt[TT * 16][FF + 1];
    __shared__ float Rt[TT * 16][FF + 1];

    int tid = threadIdx.x;
    int b = blockIdx.y, s0 = blockIdx.x * 16;

    for (int i = tid; i < FIN * FF; i += 256) { int f = i >> 5, j = i & 31; Wl[j][f] = W1[i]; }
    if (tid < FF) bl[tid] = b1[tid];
    if (tid < 64) Atl[tid] = At[tid];
    if (tid < 4) scl[tid] = sc[tid];
    // stage x tile: 8t x 16s x 32j
    #pragma unroll
    for (int i = 0; i < 16; ++i) {
        int lin = i * 256 + tid;
        int t = lin >> 9, sl = (lin >> 5) & 15, j = lin & 31;
        int s = s0 + sl;
        Xs[t][sl][j] = (s < SS) ? x[((size_t)(b * TT + t) * SS + s) * FIN + j] : 0.f;
    }
    __syncthreads();
    // xf tile into Yt + nat write
    #pragma unroll
    for (int i = 0; i < 32; ++i) {
        int lin = i * 256 + tid;
        int t = lin >> 10, sl = (lin >> 6) & 15, f = lin & 63;
        float acc = bl[f];
        #pragma unroll
        for (int j = 0; j < FIN; ++j) acc += Xs[t][sl][j] * Wl[j][f];
        Yt[t * 16 + sl][f] = acc;
        int s = s0 + sl;
        if (s < SS) xf[((size_t)(b * TT + t) * SS + s) * FF + f] = acc;
    }
    __syncthreads();
    // tmix
    float c0 = scl[0], c1 = scl[1], c2 = scl[2], c3 = scl[3];
    #pragma unroll
    for (int i = 0; i < 32; ++i) {
        int lin = i * 256 + tid;
        int t = lin >> 10, sl = (lin >> 6) & 15, f = lin & 63;
        float yv = Yt[t * 16 + sl][f];
        float p = 0.f;
        #pragma unroll
        for (int tp = 0; tp < TT; ++tp) p += Atl[t * TT + tp] * Yt[tp * 16 + sl][f];
        int s = s0 + sl;
        if (s < SS) e1[((size_t)(b * TT + t) * SS + s) * FF + f] = c0 * yv + c2 * p;
        Rt[t * 16 + sl][f] = c1 * yv + c3 * p;
    }
    __syncthreads();
    // transposed bf16 write: rT1[(bt*64+f)*KP + s]
    #pragma unroll
    for (int rr = 0; rr < 2; ++rr) {
        int row = tid * 2 + rr;
        int t = row >> 6, f = row & 63;
        unsigned short tmp[16];
        #pragma unroll
        for (int sl = 0; sl < 16; ++sl) tmp[sl] = (unsigned short)f2bf(Rt[t * 16 + sl][f]);
        unsigned short* dp = rT1 + ((size_t)(b * TT + t) * FF + f) * KP + s0;
        int4 w0, w1;
        w0.x = tmp[0] | (tmp[1] << 16); w0.y = tmp[2] | (tmp[3] << 16);
        w0.z = tmp[4] | (tmp[5] << 16); w0.w = tmp[6] | (tmp[7] << 16);
        w1.x = tmp[8] | (tmp[9] << 16); w1.y = tmp[10] | (tmp[11] << 16);
        w1.z = tmp[12] | (tmp[13] << 16); w1.w = tmp[14] | (tmp[15] << 16);
        *(int4*)dp = w0; *(int4*)(dp + 8) = w1;
    }
}

// ---------------------------------------------------------------------------
// smmA: y1 = e1 + As.rT1 (MFMA); then tmix: e2 = s0 y1 + s2 (At.y1),
//       rT2 = bf16-T(s1 y1 + s3 (At.y1)).  grid (32, 8), 4 waves, wave w: t={2w,2w+1}
// ---------------------------------------------------------------------------
__global__ __launch_bounds__(256) void smmA_k(const unsigned short* __restrict__ Asb,
                                              const unsigned short* __restrict__ rT1,
                                              const float* __restrict__ e1,
                                              const float* __restrict__ At,
                                              const float* __restrict__ sc,
                                              float* __restrict__ y1,
                                              float* __restrict__ e2,
                                              unsigned short* __restrict__ rT2) {
    __shared__ float Yt[TT * 16][FF + 1];
    __shared__ float Rt[TT * 16][FF + 1];
    __shared__ float Atl[64];
    __shared__ float scl[4];

    int tid = threadIdx.x;
    int b = blockIdx.y, s0 = blockIdx.x * 16;
    int wave = tid >> 6, lane = tid & 63;
    int l16 = lane & 15, quad = lane >> 4;

    if (tid < 64) Atl[tid] = At[tid];
    if (tid < 4) scl[tid] = sc[tid];

    const unsigned short* ap = Asb + (size_t)(s0 + l16) * KP + quad * 8;
    const unsigned short* bp0 = rT1 + ((size_t)(b * TT + 2 * wave) * FF + l16) * KP + quad * 8;
    const unsigned short* bp1 = bp0 + (size_t)FF * KP;

    floatx4 acc[2][4] = {};
    #pragma unroll 2
    for (int k0 = 0; k0 < KP; k0 += 32) {
        bf16x8 a = *(const bf16x8*)(ap + k0);
        #pragma unroll
        for (int nt = 0; nt < 4; ++nt) {
            bf16x8 b0 = *(const bf16x8*)(bp0 + (size_t)nt * 16 * KP + k0);
            acc[0][nt] = __builtin_amdgcn_mfma_f32_16x16x32_bf16(a, b0, acc[0][nt], 0, 0, 0);
            bf16x8 b1 = *(const bf16x8*)(bp1 + (size_t)nt * 16 * KP + k0);
            acc[1][nt] = __builtin_amdgcn_mfma_f32_16x16x32_bf16(a, b1, acc[1][nt], 0, 0, 0);
        }
    }

    // epilogue: y1 = acc + e1, to global + LDS
    #pragma unroll
    for (int t2 = 0; t2 < 2; ++t2) {
        int t = 2 * wave + t2;
        #pragma unroll
        for (int nt = 0; nt < 4; ++nt) {
            int f = nt * 16 + l16;
            #pragma unroll
            for (int r = 0; r < 4; ++r) {
                int sl = quad * 4 + r, s = s0 + sl;
                float ev = (s < SS) ? e1[((size_t)(b * TT + t) * SS + s) * FF + f] : 0.f;
                float yv = acc[t2][nt][r] + ev;
                if (s < SS) y1[((size_t)(b * TT + t) * SS + s) * FF + f] = yv;
                Yt[t * 16 + sl][f] = yv;
            }
        }
    }
    __syncthreads();
    float c0 = scl[0], c1 = scl[1], c2 = scl[2], c3 = scl[3];
    #pragma unroll
    for (int i = 0; i < 32; ++i) {
        int lin = i * 256 + tid;
        int t = lin >> 10, sl = (lin >> 6) & 15, f = lin & 63;
        float yv = Yt[t * 16 + sl][f];
        float p = 0.f;
        #pragma unroll
        for (int tp = 0; tp < TT; ++tp) p += Atl[t * TT + tp] * Yt[tp * 16 + sl][f];
        int s = s0 + sl;
        if (s < SS) e2[((size_t)(b * TT + t) * SS + s) * FF + f] = c0 * yv + c2 * p;
        Rt[t * 16 + sl][f] = c1 * yv + c3 * p;
    }
    __syncthreads();
    #pragma unroll
    for (int rr = 0; rr < 2; ++rr) {
        int row = tid * 2 + rr;
        int t = row >> 6, f = row & 63;
        unsigned short tmp[16];
        #pragma unroll
        for (int sl = 0; sl < 16; ++sl) tmp[sl] = (unsigned short)f2bf(Rt[t * 16 + sl][f]);
        unsigned short* dp = rT2 + ((size_t)(b * TT + t) * FF + f) * KP + s0;
        int4 w0, w1;
        w0.x = tmp[0] | (tmp[1] << 16); w0.y = tmp[2] | (tmp[3] << 16);
        w0.z = tmp[4] | (tmp[5] << 16); w0.w = tmp[6] | (tmp[7] << 16);
        w1.x = tmp[8] | (tmp[9] << 16); w1.y = tmp[10] | (tmp[11] << 16);
        w1.z = tmp[12] | (tmp[13] << 16); w1.w = tmp[14] | (tmp[15] << 16);
        *(int4*)dp = w0; *(int4*)(dp + 8) = w1;
    }
}

// ---------------------------------------------------------------------------
// smmB: y2 = e2 + As.rT2 (regs); out = tanh(v@H0 + y1@H1 + y2@H2) (MFMA over
// k=192 A-tile in LDS); if do_tmix: e1/rT1 for next layer from out.
// grid (32, 8), 4 waves.
// ---------------------------------------------------------------------------
__global__ __launch_bounds__(256) void smmB_k(const unsigned short* __restrict__ Asb,
                                              const unsigned short* __restrict__ rT2,
                                              const float* __restrict__ e2,
                                              const float* __restrict__ v,
                                              const float* __restrict__ y1,
                                              const unsigned short* __restrict__ Hl,
                                              const float* __restrict__ At,
                                              const float* __restrict__ sc,
                                              float* __restrict__ out,
                                              float* __restrict__ e1,
                                              unsigned short* __restrict__ rT1,
                                              int do_tmix) {
    __shared__ unsigned short Abf[128 * RK];   // 51200 B; overlaid by O after barrier
    __shared__ float Rt[TT * 16][FF + 1];
    __shared__ float Atl[64];
    __shared__ float scl[4];
    float* O = (float*)Abf;                    // O[row][65], 33280 B

    int tid = threadIdx.x;
    int b = blockIdx.y, s0 = blockIdx.x * 16;
    int wave = tid >> 6, lane = tid & 63;
    int l16 = lane & 15, quad = lane >> 4;

    if (tid < 64) Atl[tid] = At[tid];
    if (tid < 4) scl[tid] = sc[tid];

    // ---- spatial MFMA: y2 = e2 + As.rT2
    const unsigned short* ap = Asb + (size_t)(s0 + l16) * KP + quad * 8;
    const unsigned short* bp0 = rT2 + ((size_t)(b * TT + 2 * wave) * FF + l16) * KP + quad * 8;
    const unsigned short* bp1 = bp0 + (size_t)FF * KP;

    floatx4 acc[2][4] = {};
    #pragma unroll 2
    for (int k0 = 0; k0 < KP; k0 += 32) {
        bf16x8 a = *(const bf16x8*)(ap + k0);
        #pragma unroll
        for (int nt = 0; nt < 4; ++nt) {
            bf16x8 b0 = *(const bf16x8*)(bp0 + (size_t)nt * 16 * KP + k0);
            acc[0][nt] = __builtin_amdgcn_mfma_f32_16x16x32_bf16(a, b0, acc[0][nt], 0, 0, 0);
            bf16x8 b1 = *(const bf16x8*)(bp1 + (size_t)nt * 16 * KP + k0);
            acc[1][nt] = __builtin_amdgcn_mfma_f32_16x16x32_bf16(a, b1, acc[1][nt], 0, 0, 0);
        }
    }

    // ---- stage A-tile for H-mix: rows = t*16+sl (128), k: [0,64)=v, [64,128)=y1, [128,192)=y2
    #pragma unroll
    for (int i = 0; i < 16; ++i) {   // v part
        int lin = i * 256 + tid;
        int row = lin >> 5, fp = lin & 31;
        int t = row >> 4, sl = row & 15, s = s0 + sl;
        float2 vv = make_float2(0.f, 0.f);
        if (s < SS) vv = *(const float2*)(v + ((size_t)(b * TT + t) * SS + s) * FF + 2 * fp);
        *(unsigned*)&Abf[row * RK + 2 * fp] = f2bf(vv.x) | (f2bf(vv.y) << 16);
    }
    #pragma unroll
    for (int i = 0; i < 16; ++i) {   // y1 part
        int lin = i * 256 + tid;
        int row = lin >> 5, fp = lin & 31;
        int t = row >> 4, sl = row & 15, s = s0 + sl;
        float2 vv = make_float2(0.f, 0.f);
        if (s < SS) vv = *(const float2*)(y1 + ((size_t)(b * TT + t) * SS + s) * FF + 2 * fp);
        *(unsigned*)&Abf[row * RK + 64 + 2 * fp] = f2bf(vv.x) | (f2bf(vv.y) << 16);
    }
    // y2 part from regs (+e2)
    #pragma unroll
    for (int t2 = 0; t2 < 2; ++t2) {
        int t = 2 * wave + t2;
        #pragma unroll
        for (int nt = 0; nt < 4; ++nt) {
            int f = nt * 16 + l16;
            #pragma unroll
            for (int r = 0; r < 4; ++r) {
                int sl = quad * 4 + r, s = s0 + sl;
                float ev = (s < SS) ? e2[((size_t)(b * TT + t) * SS + s) * FF + f] : 0.f;
                float yv = acc[t2][nt][r] + ev;
                Abf[(t * 16 + sl) * RK + 128 + f] = (unsigned short)f2bf(yv);
            }
        }
    }
    __syncthreads();

    // ---- H-mix MFMA: out_rows = A[128 x 192] @ Hl^T-layout B[f][k]
    floatx4 hacc[2][4] = {};
    #pragma unroll
    for (int k0 = 0; k0 < 192; k0 += 32) {
        bf16x8 bf[4];
        #pragma unroll
        for (int nt = 0; nt < 4; ++nt)
            bf[nt] = *(const bf16x8*)(Hl + (size_t)(nt * 16 + l16) * 192 + quad * 8 + k0);
        #pragma unroll
        for (int mt2 = 0; mt2 < 2; ++mt2) {
            int mt = 2 * wave + mt2;
            bf16x8 a = *(const bf16x8*)&Abf[(mt * 16 + l16) * RK + quad * 8 + k0];
            #pragma unroll
            for (int nt = 0; nt < 4; ++nt)
                hacc[mt2][nt] = __builtin_amdgcn_mfma_f32_16x16x32_bf16(a, bf[nt], hacc[mt2][nt], 0, 0, 0);
        }
    }
    // tanh in place + nat write
    #pragma unroll
    for (int mt2 = 0; mt2 < 2; ++mt2) {
        int t = 2 * wave + mt2;
        #pragma unroll
        for (int nt = 0; nt < 4; ++nt) {
            int f = nt * 16 + l16;
            #pragma unroll
            for (int r = 0; r < 4; ++r) {
                int sl = quad * 4 + r, s = s0 + sl;
                float ov = tanhf(hacc[mt2][nt][r]);
                hacc[mt2][nt][r] = ov;
                if (s < SS) out[((size_t)(b * TT + t) * SS + s) * FF + f] = ov;
            }
        }
    }

    if (do_tmix) {
        __syncthreads();   // all ds_reads of Abf done before overlaying O
        #pragma unroll
        for (int mt2 = 0; mt2 < 2; ++mt2) {
            int t = 2 * wave + mt2;
            #pragma unroll
            for (int nt = 0; nt < 4; ++nt) {
                int f = nt * 16 + l16;
                #pragma unroll
                for (int r = 0; r < 4; ++r) {
                    int sl = quad * 4 + r;
                    O[(t * 16 + sl) * 65 + f] = hacc[mt2][nt][r];
                }
            }
        }
        __syncthreads();
        float c0 = scl[0], c1 = scl[1], c2 = scl[2], c3 = scl[3];
        #pragma unroll
        for (int i = 0; i < 32; ++i) {
            int lin = i * 256 + tid;
            int t = lin >> 10, sl = (lin >> 6) & 15, f = lin & 63;
            float yv = O[(t * 16 + sl) * 65 + f];
            float p = 0.f;
            #pragma unroll
            for (int tp = 0; tp < TT; ++tp) p += Atl[t * TT + tp] * O[(tp * 16 + sl) * 65 + f];
            int s = s0 + sl;
            if (s < SS) e1[((size_t)(b * TT + t) * SS + s) * FF + f] = c0 * yv + c2 * p;
            Rt[t * 16 + sl][f] = c1 * yv + c3 * p;
        }
        __syncthreads();
        #pragma unroll
        for (int rr = 0; rr < 2; ++rr) {
            int row = tid * 2 + rr;
            int t = row >> 6, f = row & 63;
            unsigned short tmp[16];
            #pragma unroll
            for (int sl = 0; sl < 16; ++sl) tmp[sl] = (unsigned short)f2bf(Rt[t * 16 + sl][f]);
            unsigned short* dp = rT1 + ((size_t)(b * TT + t) * FF + f) * KP + s0;
            int4 w0, w1;
            w0.x = tmp[0] | (tmp[1] << 16); w0.y = tmp[2] | (tmp[3] << 16);
            w0.z = tmp[4] | (tmp[5] << 16); w0.w = tmp[6] | (tmp[7] << 16);
            w1.x = tmp[8] | (tmp[9] << 16); w1.y = tmp[10] | (tmp[11] << 16);
            w1.z = tmp[12] | (tmp[13] << 16); w1.w = tmp[14] | (tmp[15] << 16);
            *(int4*)dp = w0; *(int4*)(dp + 8) = w1;
        }
    }
}

// ---------------------------------------------------------------------------
// zredlin2: out[b,s,f] = b2[f]*sum(m) + sum_j (sum_t m[t] xf[b,t,s,j]) * W2[f,j]
// grid (32, 8)
// ---------------------------------------------------------------------------
__global__ __launch_bounds__(256) void zredlin2_k(const float* __restrict__ xf,
                                                  const float* __restrict__ W2,
                                                  const float* __restrict__ b2,
                                                  const float* __restrict__ merge,
                                                  float* __restrict__ out) {
    __shared__ float Wl[FF][FF + 1];
    __shared__ float zt[16][FF + 1];
    __shared__ float ml[TT];
    int tid = threadIdx.x;
    int b = blockIdx.y, s0 = blockIdx.x * 16;

    for (int i = tid; i < FF * FF; i += 256) { int f = i >> 6, j = i & 63; Wl[j][f] = W2[i]; }
    if (tid < TT) ml[tid] = merge[tid];
    __syncthreads();

    float m[TT];
    #pragma unroll
    for (int t = 0; t < TT; ++t) m[t] = ml[t];
    float msum = 0.f;
    #pragma unroll
    for (int t = 0; t < TT; ++t) msum += m[t];

    #pragma unroll
    for (int p = 0; p < 4; ++p) {
        int lin = p * 256 + tid;
        int sl = lin >> 6, f = lin & 63;
        int s = s0 + sl;
        float acc = 0.f;
        if (s < SS) {
            #pragma unroll
            for (int t = 0; t < TT; ++t)
                acc += m[t] * xf[((size_t)(b * TT + t) * SS + s) * FF + f];
        }
        zt[sl][f] = acc;
    }
    __syncthreads();

    int f = tid & 63, sq = tid >> 6;
    #pragma unroll
    for (int i = 0; i < 4; ++i) {
        int sl = sq * 4 + i;
        int s = s0 + sl;
        if (s < SS) {
            float acc = b2[f] * msum;
            #pragma unroll
            for (int j = 0; j < FF; ++j) acc += zt[sl][j] * Wl[j][f];
            out[((size_t)b * SS + s) * FF + f] = acc;
        }
    }
}

// ---------------------------------------------------------------------------
extern "C" void kernel_launch(void* const* d_in, const int* in_sizes, int n_in,
                              void* d_out, int out_size, void* d_ws, size_t ws_size,
                              hipStream_t stream) {
    const float* x     = (const float*)d_in[0];
    const float* At    = (const float*)d_in[1];
    const float* As    = (const float*)d_in[2];
    const float* sc    = (const float*)d_in[3];
    const float* H     = (const float*)d_in[4];
    const float* W1    = (const float*)d_in[5];
    const float* b1    = (const float*)d_in[6];
    const float* W2    = (const float*)d_in[7];
    const float* b2    = (const float*)d_in[8];
    const float* merge = (const float*)d_in[9];
    float* out = (float*)d_out;

    char* ws = (char*)d_ws;
    unsigned short* Asb = (unsigned short*)(ws);              // 524288 B
    unsigned short* Hct = (unsigned short*)(ws + 524288);     // 73728 B
    float* xf0 = (float*)(ws + 1048576);                      // 8192000 B each
    float* xf1 = (float*)(ws + 9240576);
    float* y1  = (float*)(ws + 17432576);
    float* e1  = (float*)(ws + 25624576);
    float* e2  = (float*)(ws + 33816576);
    unsigned short* rT1 = (unsigned short*)(ws + 42008576);   // 4194304 B
    unsigned short* rT2 = (unsigned short*)(ws + 46202880);

    prep_k<<<1168, 256, 0, stream>>>(As, H, Asb, Hct);
    lin1tmix_k<<<dim3(32, BB), 256, 0, stream>>>(x, W1, b1, At, sc, xf0, e1, rT1);

    float* cur = xf0;
    float* nxt = xf1;
    for (int l = 0; l < 3; ++l) {
        smmA_k<<<dim3(32, BB), 256, 0, stream>>>(Asb, rT1, e1, At, sc, y1, e2, rT2);
        smmB_k<<<dim3(32, BB), 256, 0, stream>>>(Asb, rT2, e2, cur, y1,
                                                 Hct + (size_t)l * 64 * 192, At, sc,
                                                 nxt, e1, rT1, (l < 2) ? 1 : 0);
        float* tmp = cur; cur = nxt; nxt = tmp;
    }
    zredlin2_k<<<dim3(32, BB), 256, 0, stream>>>(cur, W2, b2, merge, out);
}